// Round 6
// baseline (24.069 us; speedup 1.0000x reference)
//
#include <hip/hip_runtime.h>
#include <math.h>

// Target: the harness's precomputed jax XLA:CPU float32 output ("ref=np").
// Model (round 6):
//   basis (EAGER, f32): t_i = RN(i * RN(1/31)) [f32 linspace]; powers via
//     glibc powf = correctly rounded (f64-emulated here);
//     basis = RN(RN(binom*t^i) * u^(3-i)), u = RN(1-t)
//   samples einsum: SMALL dot -> XLA naive LLVM-IR emitter: sequential
//     mul-then-add, NO fma        <-- the one change vs round 4
//   cross einsum:   LARGE gemm -> Eigen: k-ascending FMA chain
//   s2 = RN(RN(sy^2)+RN(sx^2)); d2 = RN(RN(p2 - 2c) + s2)
#define OPAQ(x) asm volatile("" : "+v"(x))

#define HH 256
#define WW 256
#define NS 32
#define NB 32

__global__ __launch_bounds__(256) void CurveGraphic2d_kernel(
    const float* __restrict__ in,   // [B, 4, 2] normalized key points (y,x)
    float* __restrict__ out)        // [B, H, W] fp32
{
    __shared__ float sy[NS], sx[NS], s2[NS];

    const int b   = blockIdx.x >> 8;
    const int row = blockIdx.x & 255;
    const int tid = threadIdx.x;

    if (tid < NS) {
        const int s = tid;
        // jax f32 linspace: RN(i * RN(1/31)); i=31 gives 1-2^-25 -> ties-to-even -> 1.0
        const float STEP = 1.0f / 31.0f;       // RN(1/31) compile-time
        float t = (float)s * STEP; OPAQ(t);
        float u = 1.0f - t;        OPAQ(u);
        // glibc powf (correctly rounded) -> emulate via f64 products
        float t2 = (float)((double)t * (double)t);
        float t3 = (float)((double)t * (double)t * (double)t);
        float u2 = (float)((double)u * (double)u);
        float u3 = (float)((double)u * (double)u * (double)u);
        // basis = RN( RN(binom * t^i) * u^(3-i) )
        float b0 = u3;
        float m1 = 3.0f * t;  OPAQ(m1); float b1 = m1 * u2; OPAQ(b1);
        float m2 = 3.0f * t2; OPAQ(m2); float b2 = m2 * u;  OPAQ(b2);
        float b3 = t3;

        const float* kp = in + b * 8;
        float ky0 = kp[0] * 256.0f, kx0 = kp[1] * 256.0f;   // exact (x 2^8)
        float ky1 = kp[2] * 256.0f, kx1 = kp[3] * 256.0f;
        float ky2 = kp[4] * 256.0f, kx2 = kp[5] * 256.0f;
        float ky3 = kp[6] * 256.0f, kx3 = kp[7] * 256.0f;

        // samples dot (XLA naive small-dot): sequential mul THEN add, no fma
        float p, accy, accx;
        p = b0 * ky0; OPAQ(p); accy = p;
        p = b1 * ky1; OPAQ(p); accy = accy + p; OPAQ(accy);
        p = b2 * ky2; OPAQ(p); accy = accy + p; OPAQ(accy);
        p = b3 * ky3; OPAQ(p); accy = accy + p; OPAQ(accy);

        p = b0 * kx0; OPAQ(p); accx = p;
        p = b1 * kx1; OPAQ(p); accx = accx + p; OPAQ(accx);
        p = b2 * kx2; OPAQ(p); accx = accx + p; OPAQ(accx);
        p = b3 * kx3; OPAQ(p); accx = accx + p; OPAQ(accx);

        // s2 = RN( RN(sy*sy) + RN(sx*sx) )  (elementwise reduce, no fma)
        float q1 = accy * accy; OPAQ(q1);
        float q2 = accx * accx; OPAQ(q2);
        sy[s] = accy;
        sx[s] = accx;
        s2[s] = q1 + q2;
    }
    __syncthreads();

    const float y = (float)row;
    const float x = (float)tid;
    const float p2 = y * y + x * x;   // exact (integers < 2^24)

    float mind2 = 3.4028234663852886e38f;
    #pragma unroll
    for (int s = 0; s < NS; ++s) {
        // cross (Eigen gemm K=2): c = fma(x, sx, RN(y*sy))
        float c0 = y * sy[s]; OPAQ(c0);
        float c  = fmaf(x, sx[s], c0); OPAQ(c);
        // d2 = RN( RN(p2 - 2c) + s2 ); 2c exact so fma(-2,c,p2) == RN(p2-2c)
        float e  = p2 - 2.0f * c;
        float d2 = e + s2[s];
        mind2 = fminf(mind2, d2);
    }
    mind2 = fmaxf(mind2, 0.0f);
    float md = sqrtf(mind2);              // IEEE RN
    float r  = md * 0.25f + 1e-6f;        // exact /4 ; RN(+1e-6f)
    float w  = powf(r, 0.35f);            // final op: ulp diffs un-amplified
    out[(b * HH + row) * WW + tid] = 1.0f - w;
}

extern "C" void kernel_launch(void* const* d_in, const int* in_sizes, int n_in,
                              void* d_out, int out_size, void* d_ws, size_t ws_size,
                              hipStream_t stream) {
    const float* in = (const float*)d_in[0];
    float* out = (float*)d_out;
    CurveGraphic2d_kernel<<<dim3(NB * HH), dim3(WW), 0, stream>>>(in, out);
}